// Round 5
// baseline (276.196 us; speedup 1.0000x reference)
//
#include <hip/hip_runtime.h>

// Masked smooth-L1 sum over 2^25 fp32 pairs -> scalar.
// R5: single-variable experiment — identical structure to R4 but with PLAIN
// loads (no nontemporal). Resolves attribution of the R3 win (nt vs
// structure): nt marks lines evict-first in L1/L2 and skips L3 allocation,
// which may hurt service of the ~50% L3-resident half of the inputs.

typedef float v4f __attribute__((ext_vector_type(4)));

#define ITERS 16                 // float4 pairs per thread
#define BLOCK 256
#define CHUNK (BLOCK * ITERS)    // 4096 float4 per block per array

__device__ __forceinline__ float sl1_masked(float o, float t) {
    float d = fabsf(o - t);
    float s = (d < 1.0f) ? (0.5f * d * d) : (d - 0.5f);
    return (t != 0.0f) ? s : 0.0f;
}

__device__ __forceinline__ float sl1_v4(v4f o, v4f t) {
    return sl1_masked(o.x, t.x) + sl1_masked(o.y, t.y) +
           sl1_masked(o.z, t.z) + sl1_masked(o.w, t.w);
}

__device__ __forceinline__ float block_reduce(float acc) {
    #pragma unroll
    for (int off = 32; off > 0; off >>= 1)
        acc += __shfl_down(acc, off, 64);
    __shared__ float wave_sums[BLOCK / 64];
    const int lane = threadIdx.x & 63;
    const int wave = threadIdx.x >> 6;
    if (lane == 0) wave_sums[wave] = acc;
    __syncthreads();
    return wave_sums[0] + wave_sums[1] + wave_sums[2] + wave_sums[3];
}

__global__ __launch_bounds__(BLOCK) void sl1_partial_kernel(
    const v4f* __restrict__ o4,
    const v4f* __restrict__ t4,
    float* __restrict__ partials,
    long long n4)
{
    const long long base = (long long)blockIdx.x * CHUNK + threadIdx.x;
    float acc = 0.0f;

    if (base + (ITERS - 1) * BLOCK < n4) {
        // Fast path: fully unrolled, 4-deep rotating pipeline, plain loads.
        v4f o[4], t[4];
        #pragma unroll
        for (int k = 0; k < 4; ++k) {
            o[k] = o4[base + k * BLOCK];
            t[k] = t4[base + k * BLOCK];
        }
        #pragma unroll
        for (int k = 0; k < ITERS; ++k) {
            const int s = k & 3;
            acc += sl1_v4(o[s], t[s]);
            if (k + 4 < ITERS) {
                o[s] = o4[base + (k + 4) * BLOCK];
                t[s] = t4[base + (k + 4) * BLOCK];
            }
        }
    } else {
        #pragma unroll
        for (int k = 0; k < ITERS; ++k) {
            long long idx = base + (long long)k * BLOCK;
            if (idx < n4) {
                v4f o = o4[idx];
                v4f t = t4[idx];
                acc += sl1_v4(o, t);
            }
        }
    }

    float s = block_reduce(acc);
    if (threadIdx.x == 0) partials[blockIdx.x] = s;
}

__global__ __launch_bounds__(BLOCK) void sl1_final_kernel(
    const float* __restrict__ partials,
    float* __restrict__ result,
    int n)
{
    float acc = 0.0f;
    for (int i = threadIdx.x; i < n; i += BLOCK)
        acc += partials[i];
    float s = block_reduce(acc);
    if (threadIdx.x == 0) result[0] = s;
}

extern "C" void kernel_launch(void* const* d_in, const int* in_sizes, int n_in,
                              void* d_out, int out_size, void* d_ws, size_t ws_size,
                              hipStream_t stream) {
    const v4f* o4 = (const v4f*)d_in[0];
    const v4f* t4 = (const v4f*)d_in[1];
    float* res      = (float*)d_out;
    float* partials = (float*)d_ws;

    const long long n  = (long long)in_sizes[0];  // 2^25
    const long long n4 = n / 4;                   // 8388608 = 2048 * 4096

    const int grid = (int)((n4 + CHUNK - 1) / CHUNK);  // 2048
    sl1_partial_kernel<<<grid, BLOCK, 0, stream>>>(o4, t4, partials, n4);
    sl1_final_kernel<<<1, BLOCK, 0, stream>>>(partials, res, grid);
}

// Round 6
// 249.429 us; speedup vs baseline: 1.1073x; 1.1073x over previous
//
#include <hip/hip_runtime.h>

// Masked smooth-L1 sum over 2^25 fp32 pairs -> scalar.
// R6: nt loads RESTORED (R5 proved they're worth ~28 µs: plain loads
// allocate in L2/L3 and thrash the ~50% L3-resident input half).
// New variable: 8-deep rotating pipeline -> 16 nt loads in flight per
// thread (was 8), testing whether per-wave vmcnt depth is the read-BW
// limiter (3.6 TB/s delivered vs 6.3 ceiling).

typedef float v4f __attribute__((ext_vector_type(4)));

#define ITERS 16                 // float4 pairs per thread
#define BLOCK 256
#define CHUNK (BLOCK * ITERS)    // 4096 float4 per block per array
#define DEPTH 8                  // pipeline stages (pairs in flight)

__device__ __forceinline__ float sl1_masked(float o, float t) {
    float d = fabsf(o - t);
    float s = (d < 1.0f) ? (0.5f * d * d) : (d - 0.5f);
    return (t != 0.0f) ? s : 0.0f;
}

__device__ __forceinline__ float sl1_v4(v4f o, v4f t) {
    return sl1_masked(o.x, t.x) + sl1_masked(o.y, t.y) +
           sl1_masked(o.z, t.z) + sl1_masked(o.w, t.w);
}

__device__ __forceinline__ float block_reduce(float acc) {
    #pragma unroll
    for (int off = 32; off > 0; off >>= 1)
        acc += __shfl_down(acc, off, 64);
    __shared__ float wave_sums[BLOCK / 64];
    const int lane = threadIdx.x & 63;
    const int wave = threadIdx.x >> 6;
    if (lane == 0) wave_sums[wave] = acc;
    __syncthreads();
    return wave_sums[0] + wave_sums[1] + wave_sums[2] + wave_sums[3];
}

__global__ __launch_bounds__(BLOCK) void sl1_partial_kernel(
    const v4f* __restrict__ o4,
    const v4f* __restrict__ t4,
    float* __restrict__ partials,
    long long n4)
{
    const long long base = (long long)blockIdx.x * CHUNK + threadIdx.x;
    float acc = 0.0f;

    if (base + (ITERS - 1) * BLOCK < n4) {
        // Fast path: fully unrolled, 8-deep rotating pipeline of nt loads.
        v4f o[DEPTH], t[DEPTH];
        #pragma unroll
        for (int k = 0; k < DEPTH; ++k) {
            o[k] = __builtin_nontemporal_load(&o4[base + k * BLOCK]);
            t[k] = __builtin_nontemporal_load(&t4[base + k * BLOCK]);
        }
        #pragma unroll
        for (int k = 0; k < ITERS; ++k) {
            const int s = k & (DEPTH - 1);
            acc += sl1_v4(o[s], t[s]);
            if (k + DEPTH < ITERS) {
                o[s] = __builtin_nontemporal_load(&o4[base + (k + DEPTH) * BLOCK]);
                t[s] = __builtin_nontemporal_load(&t4[base + (k + DEPTH) * BLOCK]);
            }
        }
    } else {
        #pragma unroll
        for (int k = 0; k < ITERS; ++k) {
            long long idx = base + (long long)k * BLOCK;
            if (idx < n4) {
                v4f o = __builtin_nontemporal_load(&o4[idx]);
                v4f t = __builtin_nontemporal_load(&t4[idx]);
                acc += sl1_v4(o, t);
            }
        }
    }

    float s = block_reduce(acc);
    if (threadIdx.x == 0) partials[blockIdx.x] = s;
}

__global__ __launch_bounds__(BLOCK) void sl1_final_kernel(
    const float* __restrict__ partials,
    float* __restrict__ result,
    int n)
{
    float acc = 0.0f;
    for (int i = threadIdx.x; i < n; i += BLOCK)
        acc += partials[i];
    float s = block_reduce(acc);
    if (threadIdx.x == 0) result[0] = s;
}

extern "C" void kernel_launch(void* const* d_in, const int* in_sizes, int n_in,
                              void* d_out, int out_size, void* d_ws, size_t ws_size,
                              hipStream_t stream) {
    const v4f* o4 = (const v4f*)d_in[0];
    const v4f* t4 = (const v4f*)d_in[1];
    float* res      = (float*)d_out;
    float* partials = (float*)d_ws;

    const long long n  = (long long)in_sizes[0];  // 2^25
    const long long n4 = n / 4;                   // 8388608 = 2048 * 4096

    const int grid = (int)((n4 + CHUNK - 1) / CHUNK);  // 2048
    sl1_partial_kernel<<<grid, BLOCK, 0, stream>>>(o4, t4, partials, n4);
    sl1_final_kernel<<<1, BLOCK, 0, stream>>>(partials, res, grid);
}